// Round 1
// baseline (391.396 us; speedup 1.0000x reference)
//
#include <hip/hip_runtime.h>

// Pure embedding gather:
//   indices: [16384, 50] int (flat 819200), values in [0, 1_000_000)
//   table:   [1_000_000, 64] float32  (256 MB)
//   out:     [16384, 50, 64] float32  (210 MB)
//
// Layout: each lane handles one float4 (16 B); 16 lanes per embedding row
// (64 floats = 16 float4 = 256 B). Both the gathered read (256 B contiguous
// per row) and the store are fully coalesced at the 16 B/lane sweet spot.

__global__ __launch_bounds__(256) void ShardedCXLEmbedding_gather(
    const int* __restrict__ indices,
    const float4* __restrict__ table,   // [num_emb * 16] float4
    float4* __restrict__ out,           // [n_rows * 16] float4
    int n_rows)
{
    int g = blockIdx.x * 256 + threadIdx.x;  // global float4 id
    int row = g >> 4;                        // which lookup
    int c   = g & 15;                        // which float4 within the row
    if (row < n_rows) {
        int e = indices[row];                // 16 lanes broadcast-read same addr
        out[g] = table[(long long)e * 16 + c];
    }
}

extern "C" void kernel_launch(void* const* d_in, const int* in_sizes, int n_in,
                              void* d_out, int out_size, void* d_ws, size_t ws_size,
                              hipStream_t stream) {
    const int*    indices = (const int*)d_in[0];
    const float4* table   = (const float4*)d_in[1];
    float4*       out     = (float4*)d_out;

    const int n_rows = in_sizes[0];          // 819200
    const long long n_f4 = (long long)n_rows * 16;
    const int block = 256;
    const int grid  = (int)((n_f4 + block - 1) / block);

    ShardedCXLEmbedding_gather<<<grid, block, 0, stream>>>(indices, table, out, n_rows);
}